// Round 7
// baseline (78.581 us; speedup 1.0000x reference)
//
#include <hip/hip_runtime.h>
#include <hip/hip_bf16.h>

// Dynamic conv2d: B=16, C_in=64, H=W=128, C_out=64, K=5, ks=3, pad=1.
// R7 = R6 (A-in-registers streaming GEMM) + counted-vmcnt barrier discipline:
//  - raw s_barrier with lgkmcnt(0) only (NO vmcnt drain -> loads/stores stay
//    in flight across steps)
//  - 5-slot ring + pvA/pvB double buffer: loads issued at step ri are written
//    to LDS at step ri+1 (one full step of latency cover)
// Budget: ~225 regs @ 2 waves/SIMD (launch_bounds(512,2)), LDS 83,200 B.

typedef __attribute__((ext_vector_type(8))) __bf16 bf16x8;
typedef __attribute__((ext_vector_type(16))) float f32x16;
typedef __attribute__((ext_vector_type(4))) unsigned int u32x4;

#define NB 16
#define CI 64
#define CO 64
#define HH 128
#define WW 128
#define KBANK 5
#define ASTR 36864            // shorts of aggw per b: 2m * 36ks * 2g * 32 * 8

__device__ __forceinline__ unsigned short f2bfu(float f) {
    __hip_bfloat16 h = __float2bfloat16(f);
    unsigned short s;
    __builtin_memcpy(&s, &h, 2);
    return s;
}

// ---------------- kernel 1: aggregate weights + bias ----------------
// aggw per b: [m(2)][kstep(36)][g(2)][co5(32)][j(8)]; k = ks*16+g*8+j,
// tap = k>>6, ci = k&63, co = m*32+co5. Wave A-load = contiguous 1KB.
__global__ void prep_kernel(const float* __restrict__ weights,
                            const float* __restrict__ Wbank,
                            const float* __restrict__ bbank,
                            short* __restrict__ aggw,
                            float* __restrict__ aggb) {
    int idx = blockIdx.x * 256 + threadIdx.x;          // < 16*36864
    int b   = idx / ASTR;
    int rem = idx - b * ASTR;
    int j   = rem & 7;
    int co5 = (rem >> 3) & 31;
    int g   = (rem >> 8) & 1;
    int mk  = rem >> 9;
    int m   = mk / 36;
    int ks  = mk - m * 36;
    int co  = m * 32 + co5;
    int k   = ks * 16 + g * 8 + j;
    int tap = k >> 6;
    int ci  = k & 63;
    float s = 0.f;
#pragma unroll
    for (int kk = 0; kk < KBANK; ++kk)
        s += weights[b * KBANK + kk] * Wbank[((kk * CO + co) * CI + ci) * 9 + tap];
    aggw[idx] = (short)f2bfu(s);
    if (k == 0) {
        float sb = 0.f;
#pragma unroll
        for (int kk = 0; kk < KBANK; ++kk)
            sb += weights[b * KBANK + kk] * bbank[kk * CO + co];
        aggb[b * CO + co] = sb;
    }
}

// ---------------- kernel 2: streaming conv ----------------
__device__ __forceinline__ void load16(const float* __restrict__ xb, int r,
                                       int sw, int scg, float (&pv)[16]) {
#pragma unroll
    for (int i = 0; i < 16; ++i)
        pv[i] = xb[((size_t)(scg * 16 + i) * HH + r) * WW + sw];
}

__device__ __forceinline__ void write16(short* __restrict__ slot, int sw, int scg,
                                        const float (&pv)[16]) {
#pragma unroll
    for (int h = 0; h < 2; ++h) {
        unsigned u0 = (unsigned)f2bfu(pv[h * 8 + 0]) | ((unsigned)f2bfu(pv[h * 8 + 1]) << 16);
        unsigned u1 = (unsigned)f2bfu(pv[h * 8 + 2]) | ((unsigned)f2bfu(pv[h * 8 + 3]) << 16);
        unsigned u2 = (unsigned)f2bfu(pv[h * 8 + 4]) | ((unsigned)f2bfu(pv[h * 8 + 5]) << 16);
        unsigned u3 = (unsigned)f2bfu(pv[h * 8 + 6]) | ((unsigned)f2bfu(pv[h * 8 + 7]) << 16);
        *(u32x4*)&slot[((scg * 2 + h) * 130 + sw + 1) * 8] = u32x4{u0, u1, u2, u3};
    }
}

template <int N> struct ic { static constexpr int v = N; };

__global__ __launch_bounds__(512, 2) void conv_kernel(const float* __restrict__ x,
                                                      const short* __restrict__ aggw,
                                                      const float* __restrict__ aggb,
                                                      float* __restrict__ out) {
    __shared__ short ring[5][8][130][8];               // 83,200 B

    const int t   = threadIdx.x;
    const int lin = blockIdx.x;                        // 256 blocks
    const int b     = (lin & 7) * 2 + ((lin >> 3) & 1);
    const int strip = lin >> 4;                        // 0..15
    const int r0    = strip * 8;

    const int l  = t & 63;
    const int wv = t >> 6;         // 0..7
    const int m  = wv >> 2;        // co half
    const int nq = wv & 3;         // pix quarter
    const int lm = l & 31;
    const int g  = l >> 5;

    const int sw  = t & 127;       // staging: w
    const int scg = t >> 7;        // staging: 16-ci group

    const float* xb = x + (size_t)b * CI * HH * WW;
    const short* Ab = aggw + (size_t)b * ASTR + (size_t)m * 36 * 512;

    // A-half into registers (36 x bf16x8), coalesced 1KB/wave loads
    bf16x8 A[36];
#pragma unroll
    for (int ks = 0; ks < 36; ++ks)
        A[ks] = *(const bf16x8*)(Ab + ks * 512 + l * 8);

    float bias[16];
#pragma unroll
    for (int rg = 0; rg < 16; ++rg)
        bias[rg] = aggb[b * CO + m * 32 + (rg & 3) + 8 * (rg >> 2) + 4 * g];

    // zero pix-halo (pix 0 and 129) of all 5 slots
    if (t < 80) {
        int slot = t >> 4, ch = (t >> 1) & 7, px = (t & 1) * 129;
        *(u32x4*)&ring[slot][ch][px][0] = u32x4{0u, 0u, 0u, 0u};
    }

    float pvA[16], pvB[16];
    // prologue: rows r0-1, r0, r0+1 -> slots 0,1,2 ; issue row r0+2 into pvA
    {
        float p0[16], p1[16], p2[16];
        if (r0 >= 1) load16(xb, r0 - 1, sw, scg, p0);
        else {
#pragma unroll
            for (int i = 0; i < 16; ++i) p0[i] = 0.f;
        }
        load16(xb, r0,     sw, scg, p1);
        load16(xb, r0 + 1, sw, scg, p2);
        write16(&ring[0][0][0][0], sw, scg, p0);
        write16(&ring[1][0][0][0], sw, scg, p1);
        write16(&ring[2][0][0][0], sw, scg, p2);
    }
    load16(xb, r0 + 2, sw, scg, pvA);                  // r0+2 <= 122 < 128 always
    asm volatile("s_waitcnt lgkmcnt(0)" ::: "memory");
    __builtin_amdgcn_s_barrier();
    __builtin_amdgcn_sched_barrier(0);

    // one step: fill pf with row r0+RI+3 (consumed next step), compute output
    // row r0+RI from slots RI..RI+2, write pw (row r0+RI+2) to slot (RI+3)%5.
    auto step = [&](auto RIc, float (&pf)[16], float (&pw)[16]) {
        constexpr int RI = decltype(RIc)::v;
        if (RI <= 5) {
            if (r0 + RI + 3 < 128) {
                load16(xb, r0 + RI + 3, sw, scg, pf);
            } else {
#pragma unroll
                for (int i = 0; i < 16; ++i) pf[i] = 0.f;
            }
        }
        __builtin_amdgcn_sched_barrier(0);

        const int r = r0 + RI;
        f32x16 acc = (f32x16)0.0f;
#pragma unroll
        for (int ks = 0; ks < 36; ++ks) {
            constexpr int KS = 0;  (void)KS;
            const int tap = ks >> 2, q = ks & 3;
            const int dy = tap / 3, dx = tap - dy * 3;
            const short* sb = &ring[(RI + (tap / 3)) % 5][0][0][0];
            const int pix = nq * 32 + dx + lm;
            bf16x8 bv = *(const bf16x8*)&sb[((q * 2 + g) * 130 + pix) * 8];
            acc = __builtin_amdgcn_mfma_f32_32x32x16_bf16(A[ks], bv, acc, 0, 0, 0);
        }

        const int wc = nq * 32 + lm;
#pragma unroll
        for (int rg = 0; rg < 16; ++rg) {
            int co = m * 32 + (rg & 3) + 8 * (rg >> 2) + 4 * g;
            out[(((size_t)b * CO + co) * HH + r) * WW + wc] = acc[rg] + bias[rg];
        }

        if (RI <= 6) write16(&ring[(RI + 3) % 5][0][0][0], sw, scg, pw);

        asm volatile("s_waitcnt lgkmcnt(0)" ::: "memory");
        __builtin_amdgcn_s_barrier();
        __builtin_amdgcn_sched_barrier(0);
    };

    step(ic<0>{}, pvB, pvA);
    step(ic<1>{}, pvA, pvB);
    step(ic<2>{}, pvB, pvA);
    step(ic<3>{}, pvA, pvB);
    step(ic<4>{}, pvB, pvA);
    step(ic<5>{}, pvA, pvB);
    step(ic<6>{}, pvB, pvA);
    step(ic<7>{}, pvA, pvB);
}

extern "C" void kernel_launch(void* const* d_in, const int* in_sizes, int n_in,
                              void* d_out, int out_size, void* d_ws, size_t ws_size,
                              hipStream_t stream) {
    const float* x       = (const float*)d_in[0];
    const float* weights = (const float*)d_in[1];
    const float* Wbank   = (const float*)d_in[2];
    const float* bbank   = (const float*)d_in[3];
    float* out = (float*)d_out;

    short* aggw = (short*)d_ws;                          // 1,179,648 B
    float* aggb = (float*)((char*)d_ws + 1179648);       //     4,096 B

    prep_kernel<<<dim3((NB * ASTR) / 256), dim3(256), 0, stream>>>(weights, Wbank, bbank, aggw, aggb);
    conv_kernel<<<dim3(256), dim3(512), 0, stream>>>(x, aggw, aggb, out);
}